// Round 1
// baseline (713.935 us; speedup 1.0000x reference)
//
#include <hip/hip_runtime.h>
#include <hip/hip_bf16.h>

// ---------------------------------------------------------------------------
// EdgeFtLayer fused kernel for MI355X (gfx950).
//
// Math (per edge e with src s, dst d):
//   cat[e]      = [ x[d] (128) | edge_attr[e] (64) | x[s] (128) ]   (K = 320)
//   logits[e]   = prelu(cat @ W_a)            -> ex = exp(logits)   (no max-sub;
//                                                fp32 range is plenty)
//   msg[e]      = cat @ W_T
//   new_e[e]    = cat @ [W_e; W_ee; W_e]      (cols 256..319 of combined B)
//   num[d][c]  += ex*msg ; den[d][c] += ex    (atomic f32)
//   new_x[d]    = num/den (+b_T)              (finalize kernel)
//
// Combined B is [320 K x 320 N]: cols 0..127 = W_a, 128..255 = W_T,
// 256..319 = stacked [W_e; W_ee; W_e].
// ---------------------------------------------------------------------------

typedef float  f32x4   __attribute__((ext_vector_type(4)));
typedef __bf16 bf16x8  __attribute__((ext_vector_type(8)));
typedef unsigned short ushort8_t __attribute__((ext_vector_type(8)));

#define ROWSTRIDE 328   // 320 + 8 bf16 pad: row stride = 164 dwords -> 4-bank
                        // shift per row -> only 2-way conflicts (free) on
                        // ds_read_b128 A-frag loads.

__device__ __forceinline__ unsigned short f2bf(float f) {
  // round-to-nearest-even f32 -> bf16 (inputs are finite; no NaN handling)
  unsigned int u = __float_as_uint(f);
  return (unsigned short)((u + 0x7FFFu + ((u >> 16) & 1u)) >> 16);
}

__device__ __forceinline__ void store_bf4(unsigned short* p, float4 v) {
  ushort4 u;
  u.x = f2bf(v.x); u.y = f2bf(v.y); u.z = f2bf(v.z); u.w = f2bf(v.w);
  *(ushort4*)p = u;
}

// ---------------------------------------------------------------------------
// Kernel 1: pack combined weight matrix into bf16, pre-swizzled into the MFMA
// B-fragment order so the GEMM does one 16B load per B frag:
//   Bp[ ((nt*10 + kt)*64 + lane)*8 + j ] = B[kt*32 + (lane>>4)*8 + j][nt*16 + (lane&15)]
// ---------------------------------------------------------------------------
__global__ void prep_b_kernel(const float* __restrict__ Wa,
                              const float* __restrict__ Wt,
                              const float* __restrict__ We,
                              const float* __restrict__ Wee,
                              unsigned short* __restrict__ Bp) {
  int pe = blockIdx.x * 256 + threadIdx.x;          // 0 .. 102399
  int j    = pe & 7;
  int lane = (pe >> 3) & 63;
  int kt   = (pe >> 9) % 10;
  int nt   = pe / 5120;
  int k = kt * 32 + ((lane >> 4) << 3) + j;         // 0..319
  int n = nt * 16 + (lane & 15);                    // 0..319
  float v;
  if (n < 128) {
    v = Wa[k * 128 + n];
  } else if (n < 256) {
    v = Wt[k * 128 + (n - 128)];
  } else {
    int c = n - 256;
    if (k < 128)      v = We[k * 64 + c];
    else if (k < 192) v = Wee[(k - 128) * 64 + c];
    else              v = We[(k - 192) * 64 + c];
  }
  Bp[pe] = f2bf(v);
}

// ---------------------------------------------------------------------------
// Kernel 2: fused gather + GEMM + epilogue. 64 edges / block, 256 threads.
// Wave w owns n-tiles {w, w+4, w+8, w+12, w+16}: logit tile i and msg tile
// i+2 hold the SAME output column in the same lane/reg -> in-register epilogue.
// ---------------------------------------------------------------------------
__global__ __launch_bounds__(256, 2) void fused_edge_kernel(
    const float* __restrict__ x,
    const int*   __restrict__ ei,       // [2, E] int32
    const float* __restrict__ ea,
    const unsigned short* __restrict__ Bp,
    float* __restrict__ num,
    float* __restrict__ den,
    float* __restrict__ out_e,
    const float* __restrict__ a_prelu,
    int E) {
  __shared__ unsigned short At[64 * ROWSTRIDE];   // 41,984 B
  __shared__ int s_src[64];
  __shared__ int s_dst[64];

  const int tid = threadIdx.x;
  const int eb  = blockIdx.x * 64;

  if (tid < 64) {
    int e = eb + tid;
    int s = 0, d = 0;
    if (e < E) { s = ei[e]; d = ei[E + e]; }
    s_src[tid] = s;
    s_dst[tid] = d;
  }
  __syncthreads();

  const float4* x4  = (const float4*)x;
  const float4* ea4 = (const float4*)ea;

  // gather x[dst] -> cols [0,128)
  #pragma unroll
  for (int i = tid; i < 2048; i += 256) {
    int r = i >> 5, c4 = i & 31;
    float4 v = {0.f, 0.f, 0.f, 0.f};
    if (eb + r < E) v = x4[(size_t)s_dst[r] * 32 + c4];
    store_bf4(&At[r * ROWSTRIDE + c4 * 4], v);
  }
  // gather edge_attr -> cols [128,192)
  #pragma unroll
  for (int i = tid; i < 1024; i += 256) {
    int r = i >> 4, c4 = i & 15;
    float4 v = {0.f, 0.f, 0.f, 0.f};
    if (eb + r < E) v = ea4[(size_t)(eb + r) * 16 + c4];
    store_bf4(&At[r * ROWSTRIDE + 128 + c4 * 4], v);
  }
  // gather x[src] -> cols [192,320)
  #pragma unroll
  for (int i = tid; i < 2048; i += 256) {
    int r = i >> 5, c4 = i & 31;
    float4 v = {0.f, 0.f, 0.f, 0.f};
    if (eb + r < E) v = x4[(size_t)s_src[r] * 32 + c4];
    store_bf4(&At[r * ROWSTRIDE + 192 + c4 * 4], v);
  }
  __syncthreads();

  const int w    = tid >> 6;        // wave id 0..3
  const int l    = tid & 63;        // lane
  const int lrow = l & 15;          // A row / B col within tile
  const int lk8  = (l >> 4) << 3;   // k offset within 32-chunk

  f32x4 acc[4][5];
  #pragma unroll
  for (int mt = 0; mt < 4; ++mt)
    #pragma unroll
    for (int i = 0; i < 5; ++i)
      acc[mt][i] = (f32x4){0.f, 0.f, 0.f, 0.f};

  for (int kc = 0; kc < 10; ++kc) {
    const int kbase = kc * 32 + lk8;
    bf16x8 av[4];
    #pragma unroll
    for (int mt = 0; mt < 4; ++mt) {
      ushort8_t u = *(const ushort8_t*)&At[(mt * 16 + lrow) * ROWSTRIDE + kbase];
      av[mt] = __builtin_bit_cast(bf16x8, u);
    }
    #pragma unroll
    for (int i = 0; i < 5; ++i) {
      const int nt = w + 4 * i;
      ushort8_t ub = *(const ushort8_t*)&Bp[(((nt * 10 + kc) * 64) + l) * 8];
      bf16x8 bv = __builtin_bit_cast(bf16x8, ub);
      #pragma unroll
      for (int mt = 0; mt < 4; ++mt)
        acc[mt][i] = __builtin_amdgcn_mfma_f32_16x16x32_bf16(av[mt], bv, acc[mt][i], 0, 0, 0);
    }
  }

  // ------------------- epilogue -------------------
  // C layout: row = (lane>>4)*4 + reg, col = lane&15   [guide §3, m89-verified]
  const float slope = a_prelu[0];
  const int rbase = (l >> 4) << 2;
  const int ccol  = l & 15;

  #pragma unroll
  for (int mt = 0; mt < 4; ++mt) {
    const int m0 = mt * 16 + rbase;
    // new_e_feat: tile i=4 is global n-tile w+16 -> e-col = w*16 + ccol
    #pragma unroll
    for (int r = 0; r < 4; ++r) {
      int m = m0 + r;
      if (eb + m < E)
        out_e[(size_t)(eb + m) * 64 + w * 16 + ccol] = acc[mt][4][r];
    }
    // attention numerator/denominator
    #pragma unroll
    for (int i2 = 0; i2 < 2; ++i2) {
      const int c = (w + 4 * i2) * 16 + ccol;   // output column 0..127
      #pragma unroll
      for (int r = 0; r < 4; ++r) {
        int m = m0 + r;
        if (eb + m < E) {
          float lg = acc[mt][i2][r];
          float ex = __expf(lg >= 0.f ? lg : slope * lg);
          float mg = acc[mt][i2 + 2][r];
          int d = s_dst[m];
          unsafeAtomicAdd(&num[(size_t)d * 128 + c], ex * mg);
          unsafeAtomicAdd(&den[(size_t)d * 128 + c], ex);
        }
      }
    }
  }
}

// ---------------------------------------------------------------------------
// Kernel 3: finalize new_x = num / (den + 1e-16) + b_T
// ---------------------------------------------------------------------------
__global__ void finalize_kernel(const float* __restrict__ num,
                                const float* __restrict__ den,
                                const float* __restrict__ bT,
                                float* __restrict__ out_x,
                                int total) {
  int i = blockIdx.x * 256 + threadIdx.x;
  if (i < total)
    out_x[i] = num[i] / (den[i] + 1e-16f) + bT[i & 127];
}

extern "C" void kernel_launch(void* const* d_in, const int* in_sizes, int n_in,
                              void* d_out, int out_size, void* d_ws, size_t ws_size,
                              hipStream_t stream) {
  const float* x   = (const float*)d_in[0];
  const int*   ei  = (const int*)d_in[1];   // int -> int32 per harness contract
  const float* ea  = (const float*)d_in[2];
  const float* Wa  = (const float*)d_in[3];
  const float* Wt  = (const float*)d_in[4];
  const float* bT  = (const float*)d_in[5];
  const float* We  = (const float*)d_in[6];
  const float* Wee = (const float*)d_in[7];
  const float* ap  = (const float*)d_in[8];

  const int N = in_sizes[0] / 128;          // 50000
  const int E = in_sizes[1] / 2;            // 500000

  // workspace layout: [Bp: 320*320 bf16 = 204800 B][num: N*128 f32][den: N*128 f32]
  unsigned short* Bp = (unsigned short*)d_ws;
  float* num = (float*)((char*)d_ws + 204800);
  float* den = num + (size_t)N * 128;

  float* out_x = (float*)d_out;
  float* out_e = out_x + (size_t)N * 128;

  hipMemsetAsync(num, 0, (size_t)N * 128 * 2 * sizeof(float), stream);
  prep_b_kernel<<<400, 256, 0, stream>>>(Wa, Wt, We, Wee, Bp);
  fused_edge_kernel<<<(E + 63) / 64, 256, 0, stream>>>(x, ei, ea, Bp, num, den,
                                                       out_e, ap, E);
  finalize_kernel<<<((size_t)N * 128 + 255) / 256, 256, 0, stream>>>(
      num, den, bT, out_x, N * 128);
}

// Round 2
// 692.657 us; speedup vs baseline: 1.0307x; 1.0307x over previous
//
#include <hip/hip_runtime.h>
#include <hip/hip_bf16.h>

// ---------------------------------------------------------------------------
// EdgeFtLayer fused kernel for MI355X (gfx950).  Round 2: dst-sorted edges.
//
// Pipeline per call:
//   1. memset   num/den/cnt = 0
//   2. prep_b   pack combined [320x320] weight matrix, MFMA-B-frag order, bf16
//   3. hist     cnt[d] = degree(d)
//   4. scan     cur[d] = exclusive prefix sum of cnt (single 1024-thr block)
//   5. scatter  perm[pos] = edge id, sorted by dst  (counting sort)
//   6. fused    per 64 sorted edges: gather cat -> LDS bf16, one 320x320 GEMM
//               (MFMA 16x16x32), epilogue: new_e direct store; ex / ex*msg
//               segment-reduced over sorted-dst runs in LDS -> few atomics
//   7. finalize new_x = num/(den+1e-16) + b_T
//
// Round-1 counters showed the epilogue's 128M f32 atomics were the bound
// (WRITE_SIZE 625 MB, MfmaUtil 8%). Sorted runs cut atomics ~7.5x.
// ---------------------------------------------------------------------------

typedef float  f32x4   __attribute__((ext_vector_type(4)));
typedef __bf16 bf16x8  __attribute__((ext_vector_type(8)));
typedef unsigned short ushort8_t __attribute__((ext_vector_type(8)));

#define ROWSTRIDE 328   // bf16 elems: 320 + 8 pad -> 2-way-only LDS conflicts
#define RED_STRIDE 132  // f32 elems: 128 + 4 pad -> quads hit different banks

__device__ __forceinline__ unsigned short f2bf(float f) {
  unsigned int u = __float_as_uint(f);
  return (unsigned short)((u + 0x7FFFu + ((u >> 16) & 1u)) >> 16);
}

__device__ __forceinline__ void store_bf4(unsigned short* p, float4 v) {
  ushort4 u;
  u.x = f2bf(v.x); u.y = f2bf(v.y); u.z = f2bf(v.z); u.w = f2bf(v.w);
  *(ushort4*)p = u;
}

// ---------------------------------------------------------------------------
// Weight pack: Bp[((nt*10+kt)*64+lane)*8+j] = B[kt*32+(lane>>4)*8+j][nt*16+(lane&15)]
// cols 0..127 = W_a, 128..255 = W_T, 256..319 = [W_e; W_ee; W_e] stacked in K.
// ---------------------------------------------------------------------------
__global__ void prep_b_kernel(const float* __restrict__ Wa,
                              const float* __restrict__ Wt,
                              const float* __restrict__ We,
                              const float* __restrict__ Wee,
                              unsigned short* __restrict__ Bp) {
  int pe = blockIdx.x * 256 + threadIdx.x;          // 0 .. 102399
  int j    = pe & 7;
  int lane = (pe >> 3) & 63;
  int kt   = (pe >> 9) % 10;
  int nt   = pe / 5120;
  int k = kt * 32 + ((lane >> 4) << 3) + j;
  int n = nt * 16 + (lane & 15);
  float v;
  if (n < 128) {
    v = Wa[k * 128 + n];
  } else if (n < 256) {
    v = Wt[k * 128 + (n - 128)];
  } else {
    int c = n - 256;
    if (k < 128)      v = We[k * 64 + c];
    else if (k < 192) v = Wee[(k - 128) * 64 + c];
    else              v = We[(k - 192) * 64 + c];
  }
  Bp[pe] = f2bf(v);
}

// --------------------------- counting sort by dst ---------------------------
__global__ void hist_kernel(const int* __restrict__ ei, int* __restrict__ cnt,
                            int E) {
  int e = blockIdx.x * 256 + threadIdx.x;
  if (e < E) atomicAdd(&cnt[ei[E + e]], 1);
}

// single block, 1024 threads, 49 items each: exclusive scan of cnt[0..n) -> cur
__global__ void scan_kernel(const int* __restrict__ cnt, int* __restrict__ cur,
                            int n) {
  __shared__ int ls[1024];
  const int t = threadIdx.x;
  const int base = t * 49;
  int s = 0;
  for (int i = 0; i < 49; ++i) {
    int idx = base + i;
    if (idx < n) s += cnt[idx];
  }
  ls[t] = s;
  __syncthreads();
  for (int off = 1; off < 1024; off <<= 1) {
    int v = (t >= off) ? ls[t - off] : 0;
    __syncthreads();
    ls[t] += v;
    __syncthreads();
  }
  int run = (t == 0) ? 0 : ls[t - 1];
  for (int i = 0; i < 49; ++i) {
    int idx = base + i;
    if (idx < n) {
      int v = cnt[idx];
      cur[idx] = run;
      run += v;
    }
  }
}

__global__ void scatter_kernel(const int* __restrict__ ei, int* __restrict__ cur,
                               int* __restrict__ perm, int E) {
  int e = blockIdx.x * 256 + threadIdx.x;
  if (e < E) {
    int d = ei[E + e];
    int pos = atomicAdd(&cur[d], 1);
    perm[pos] = e;
  }
}

// ---------------------------------------------------------------------------
// Fused gather + GEMM + segmented-reduction epilogue. 64 sorted edges / block.
// Wave w owns n-tiles {w, w+4, w+8, w+12, w+16}.
// ---------------------------------------------------------------------------
__global__ __launch_bounds__(256, 2) void fused_edge_kernel(
    const float* __restrict__ x,
    const int*   __restrict__ ei,
    const float* __restrict__ ea,
    const int*   __restrict__ perm,
    const unsigned short* __restrict__ Bp,
    float* __restrict__ num,
    float* __restrict__ den,
    float* __restrict__ out_e,
    const float* __restrict__ a_prelu,
    int E) {
  __shared__ __align__(16) char smem[64 * ROWSTRIDE * 2];   // 41,984 B
  unsigned short* At = (unsigned short*)smem;               // staging view
  float* red = (float*)smem;                                // epilogue view
  __shared__ int s_src[64];
  __shared__ int s_dst[64];
  __shared__ int s_eid[64];

  const int tid = threadIdx.x;
  const int eb  = blockIdx.x * 64;
  const int nvalid = min(64, E - eb);

  if (tid < 64) {
    int e = 0, s = 0, d = 0;
    if (tid < nvalid) {
      e = perm[eb + tid];
      s = ei[e];
      d = ei[E + e];
    }
    s_eid[tid] = e;
    s_src[tid] = s;
    s_dst[tid] = d;
  }
  __syncthreads();

  const float4* x4  = (const float4*)x;
  const float4* ea4 = (const float4*)ea;

  // gather x[dst] -> cols [0,128)   (sorted dst -> strong L1 reuse)
  #pragma unroll
  for (int i = tid; i < 2048; i += 256) {
    int r = i >> 5, c4 = i & 31;
    float4 v = {0.f, 0.f, 0.f, 0.f};
    if (r < nvalid) v = x4[(size_t)s_dst[r] * 32 + c4];
    store_bf4(&At[r * ROWSTRIDE + c4 * 4], v);
  }
  // gather edge_attr -> cols [128,192)
  #pragma unroll
  for (int i = tid; i < 1024; i += 256) {
    int r = i >> 4, c4 = i & 15;
    float4 v = {0.f, 0.f, 0.f, 0.f};
    if (r < nvalid) v = ea4[(size_t)s_eid[r] * 16 + c4];
    store_bf4(&At[r * ROWSTRIDE + 128 + c4 * 4], v);
  }
  // gather x[src] -> cols [192,320)
  #pragma unroll
  for (int i = tid; i < 2048; i += 256) {
    int r = i >> 5, c4 = i & 31;
    float4 v = {0.f, 0.f, 0.f, 0.f};
    if (r < nvalid) v = x4[(size_t)s_src[r] * 32 + c4];
    store_bf4(&At[r * ROWSTRIDE + 192 + c4 * 4], v);
  }
  __syncthreads();

  const int w    = tid >> 6;
  const int l    = tid & 63;
  const int lrow = l & 15;
  const int lk8  = (l >> 4) << 3;

  f32x4 acc[4][5];
  #pragma unroll
  for (int mt = 0; mt < 4; ++mt)
    #pragma unroll
    for (int i = 0; i < 5; ++i)
      acc[mt][i] = (f32x4){0.f, 0.f, 0.f, 0.f};

  for (int kc = 0; kc < 10; ++kc) {
    const int kbase = kc * 32 + lk8;
    bf16x8 av[4];
    #pragma unroll
    for (int mt = 0; mt < 4; ++mt) {
      ushort8_t u = *(const ushort8_t*)&At[(mt * 16 + lrow) * ROWSTRIDE + kbase];
      av[mt] = __builtin_bit_cast(bf16x8, u);
    }
    #pragma unroll
    for (int i = 0; i < 5; ++i) {
      const int nt = w + 4 * i;
      ushort8_t ub = *(const ushort8_t*)&Bp[(((nt * 10 + kc) * 64) + l) * 8];
      bf16x8 bv = __builtin_bit_cast(bf16x8, ub);
      #pragma unroll
      for (int mt = 0; mt < 4; ++mt)
        acc[mt][i] = __builtin_amdgcn_mfma_f32_16x16x32_bf16(av[mt], bv, acc[mt][i], 0, 0, 0);
    }
  }

  // ------------------- epilogue -------------------
  // C layout: row = (lane>>4)*4 + reg, col = lane&15
  const float slope = a_prelu[0];
  const int rbase = (l >> 4) << 2;
  const int ccol  = l & 15;

  // new_e_feat (tile i=4 is global n-tile w+16 -> e-col = w*16 + ccol)
  #pragma unroll
  for (int mt = 0; mt < 4; ++mt) {
    const int m0 = mt * 16 + rbase;
    #pragma unroll
    for (int r = 0; r < 4; ++r) {
      int m = m0 + r;
      if (m < nvalid)
        out_e[(size_t)s_eid[m] * 64 + w * 16 + ccol] = acc[mt][4][r];
    }
  }

  // ex = exp(prelu(logits)); keep in registers for both passes
  float exv[4][2][4];
  #pragma unroll
  for (int mt = 0; mt < 4; ++mt)
    #pragma unroll
    for (int i2 = 0; i2 < 2; ++i2)
      #pragma unroll
      for (int r = 0; r < 4; ++r) {
        float lg = acc[mt][i2][r];
        exv[mt][i2][r] = __expf(lg >= 0.f ? lg : slope * lg);
      }

  __syncthreads();   // all waves done reading At; safe to recycle as `red`

  // ---- pass 1: num = segmented sum of ex*msg over sorted-dst runs ----
  #pragma unroll
  for (int mt = 0; mt < 4; ++mt) {
    const int m0 = mt * 16 + rbase;
    #pragma unroll
    for (int i2 = 0; i2 < 2; ++i2) {
      const int c = (w + 4 * i2) * 16 + ccol;
      #pragma unroll
      for (int r = 0; r < 4; ++r)
        red[(m0 + r) * RED_STRIDE + c] = exv[mt][i2][r] * acc[mt][i2 + 2][r];
    }
  }
  __syncthreads();
  {
    const int c  = tid & 127;
    const int r0 = (tid >> 7) * 32;
    const int r1 = min(r0 + 32, nvalid);
    float sum = 0.f;
    for (int r = r0; r < r1; ++r) {
      sum += red[r * RED_STRIDE + c];
      if (r == r1 - 1 || s_dst[r + 1] != s_dst[r]) {
        unsafeAtomicAdd(&num[(size_t)s_dst[r] * 128 + c], sum);
        sum = 0.f;
      }
    }
  }
  __syncthreads();

  // ---- pass 2: den = segmented sum of ex ----
  #pragma unroll
  for (int mt = 0; mt < 4; ++mt) {
    const int m0 = mt * 16 + rbase;
    #pragma unroll
    for (int i2 = 0; i2 < 2; ++i2) {
      const int c = (w + 4 * i2) * 16 + ccol;
      #pragma unroll
      for (int r = 0; r < 4; ++r)
        red[(m0 + r) * RED_STRIDE + c] = exv[mt][i2][r];
    }
  }
  __syncthreads();
  {
    const int c  = tid & 127;
    const int r0 = (tid >> 7) * 32;
    const int r1 = min(r0 + 32, nvalid);
    float sum = 0.f;
    for (int r = r0; r < r1; ++r) {
      sum += red[r * RED_STRIDE + c];
      if (r == r1 - 1 || s_dst[r + 1] != s_dst[r]) {
        unsafeAtomicAdd(&den[(size_t)s_dst[r] * 128 + c], sum);
        sum = 0.f;
      }
    }
  }
}

// ---------------------------------------------------------------------------
__global__ void finalize_kernel(const float* __restrict__ num,
                                const float* __restrict__ den,
                                const float* __restrict__ bT,
                                float* __restrict__ out_x,
                                int total) {
  int i = blockIdx.x * 256 + threadIdx.x;
  if (i < total)
    out_x[i] = num[i] / (den[i] + 1e-16f) + bT[i & 127];
}

extern "C" void kernel_launch(void* const* d_in, const int* in_sizes, int n_in,
                              void* d_out, int out_size, void* d_ws, size_t ws_size,
                              hipStream_t stream) {
  const float* x   = (const float*)d_in[0];
  const int*   ei  = (const int*)d_in[1];
  const float* ea  = (const float*)d_in[2];
  const float* Wa  = (const float*)d_in[3];
  const float* Wt  = (const float*)d_in[4];
  const float* bT  = (const float*)d_in[5];
  const float* We  = (const float*)d_in[6];
  const float* Wee = (const float*)d_in[7];
  const float* ap  = (const float*)d_in[8];

  const int N = in_sizes[0] / 128;          // 50000
  const int E = in_sizes[1] / 2;            // 500000

  // workspace layout (bytes):
  //   [Bp 204800][num 25.6M][den 25.6M][cnt 200704][cur 200704][perm 2M]
  char* ws = (char*)d_ws;
  unsigned short* Bp = (unsigned short*)ws;
  float* num = (float*)(ws + 204800);
  float* den = num + (size_t)N * 128;
  int* cnt   = (int*)(ws + 204800 + (size_t)N * 128 * 8);
  int* cur   = cnt + 50176;
  int* perm  = cur + 50176;

  float* out_x = (float*)d_out;
  float* out_e = out_x + (size_t)N * 128;

  // zero num, den, cnt in one contiguous memset
  hipMemsetAsync(num, 0, (size_t)N * 128 * 8 + 50176 * sizeof(int), stream);
  prep_b_kernel<<<400, 256, 0, stream>>>(Wa, Wt, We, Wee, Bp);
  hist_kernel<<<(E + 255) / 256, 256, 0, stream>>>(ei, cnt, E);
  scan_kernel<<<1, 1024, 0, stream>>>(cnt, cur, N);
  scatter_kernel<<<(E + 255) / 256, 256, 0, stream>>>(ei, cur, perm, E);
  fused_edge_kernel<<<(E + 63) / 64, 256, 0, stream>>>(x, ei, ea, perm, Bp,
                                                       num, den, out_e, ap, E);
  finalize_kernel<<<((size_t)N * 128 + 255) / 256, 256, 0, stream>>>(
      num, den, bT, out_x, N * 128);
}

// Round 3
// 585.768 us; speedup vs baseline: 1.2188x; 1.1825x over previous
//
#include <hip/hip_runtime.h>
#include <hip/hip_bf16.h>

// ---------------------------------------------------------------------------
// EdgeFtLayer fused kernel for MI355X (gfx950).  Round 3.
//
// Pipeline per call:
//   1. memset    num/den/cnt = 0
//   2. prep_b    pack combined [320x320] weight matrix, MFMA-B-frag order, bf16
//   3. xbf16     pre-convert x (f32 -> bf16), 12.8 MB
//   4. hist      cnt[d] = degree(d)
//   5. scan1/2/3 parallel exclusive prefix sum (196-block reduce, 256-scan,
//                per-block scan+offset)  [round-2's single-block scan was a
//                one-CU serial bottleneck]
//   6. scatter   counting-sort by dst; emits sorted eid/src/dst arrays so the
//                fused kernel has no perm->ei indirection
//   7. fused     per 64 sorted edges: gather cat -> LDS bf16, 320x320 GEMM
//                (MFMA 16x16x32), epilogue: new_e direct store; ex / ex*msg
//                segment-reduced over sorted-dst runs in LDS -> few atomics
//   8. finalize  new_x = num/(den+1e-16) + b_T
// ---------------------------------------------------------------------------

typedef float  f32x4   __attribute__((ext_vector_type(4)));
typedef __bf16 bf16x8  __attribute__((ext_vector_type(8)));
typedef unsigned short ushort8_t __attribute__((ext_vector_type(8)));

#define ROWSTRIDE 328   // bf16 elems: 320 + 8 pad -> 2-way-only LDS conflicts
#define RED_STRIDE 132  // f32 elems: 128 + 4 pad

__device__ __forceinline__ unsigned short f2bf(float f) {
  unsigned int u = __float_as_uint(f);
  return (unsigned short)((u + 0x7FFFu + ((u >> 16) & 1u)) >> 16);
}

__device__ __forceinline__ void store_bf4(unsigned short* p, float4 v) {
  ushort4 u;
  u.x = f2bf(v.x); u.y = f2bf(v.y); u.z = f2bf(v.z); u.w = f2bf(v.w);
  *(ushort4*)p = u;
}

// ---------------------------------------------------------------------------
__global__ void prep_b_kernel(const float* __restrict__ Wa,
                              const float* __restrict__ Wt,
                              const float* __restrict__ We,
                              const float* __restrict__ Wee,
                              unsigned short* __restrict__ Bp) {
  int pe = blockIdx.x * 256 + threadIdx.x;          // 0 .. 102399
  int j    = pe & 7;
  int lane = (pe >> 3) & 63;
  int kt   = (pe >> 9) % 10;
  int nt   = pe / 5120;
  int k = kt * 32 + ((lane >> 4) << 3) + j;
  int n = nt * 16 + (lane & 15);
  float v;
  if (n < 128) {
    v = Wa[k * 128 + n];
  } else if (n < 256) {
    v = Wt[k * 128 + (n - 128)];
  } else {
    int c = n - 256;
    if (k < 128)      v = We[k * 64 + c];
    else if (k < 192) v = Wee[(k - 128) * 64 + c];
    else              v = We[(k - 192) * 64 + c];
  }
  Bp[pe] = f2bf(v);
}

// --------------------------- x -> bf16 pre-convert --------------------------
__global__ void xbf16_kernel(const float* __restrict__ x,
                             unsigned short* __restrict__ xb, int total4) {
  int i = blockIdx.x * 256 + threadIdx.x;
  if (i < total4) {
    float4 v = ((const float4*)x)[i];
    store_bf4(&xb[(size_t)i * 4], v);
  }
}

// --------------------------- counting sort by dst ---------------------------
__global__ void hist_kernel(const int* __restrict__ ei, int* __restrict__ cnt,
                            int E) {
  int e = blockIdx.x * 256 + threadIdx.x;
  if (e < E) atomicAdd(&cnt[ei[E + e]], 1);
}

__global__ void scan1_kernel(const int* __restrict__ cnt,
                             int* __restrict__ bsum, int n) {
  __shared__ int ls[256];
  int t = threadIdx.x;
  int i = blockIdx.x * 256 + t;
  ls[t] = (i < n) ? cnt[i] : 0;
  __syncthreads();
  for (int off = 128; off > 0; off >>= 1) {
    if (t < off) ls[t] += ls[t + off];
    __syncthreads();
  }
  if (t == 0) bsum[blockIdx.x] = ls[0];
}

__global__ void scan2_kernel(int* __restrict__ bsum, int nb) {
  __shared__ int ls[256];
  int t = threadIdx.x;
  int v = (t < nb) ? bsum[t] : 0;
  ls[t] = v;
  __syncthreads();
  for (int off = 1; off < 256; off <<= 1) {
    int u = (t >= off) ? ls[t - off] : 0;
    __syncthreads();
    ls[t] += u;
    __syncthreads();
  }
  if (t < nb) bsum[t] = ls[t] - v;   // exclusive
}

__global__ void scan3_kernel(const int* __restrict__ cnt,
                             const int* __restrict__ bsum,
                             int* __restrict__ cur, int n) {
  __shared__ int ls[256];
  int t = threadIdx.x;
  int i = blockIdx.x * 256 + t;
  int v = (i < n) ? cnt[i] : 0;
  ls[t] = v;
  __syncthreads();
  for (int off = 1; off < 256; off <<= 1) {
    int u = (t >= off) ? ls[t - off] : 0;
    __syncthreads();
    ls[t] += u;
    __syncthreads();
  }
  if (i < n) cur[i] = ls[t] - v + bsum[blockIdx.x];
}

__global__ void scatter_kernel(const int* __restrict__ ei, int* __restrict__ cur,
                               int* __restrict__ eid_s, int* __restrict__ src_s,
                               int* __restrict__ dst_s, int E) {
  int e = blockIdx.x * 256 + threadIdx.x;
  if (e < E) {
    int s = ei[e];
    int d = ei[E + e];
    int pos = atomicAdd(&cur[d], 1);
    eid_s[pos] = e;
    src_s[pos] = s;
    dst_s[pos] = d;
  }
}

// ---------------------------------------------------------------------------
// Fused gather + GEMM + segmented-reduction epilogue. 64 sorted edges / block.
// Wave w owns n-tiles {w, w+4, w+8, w+12, w+16}.
// ---------------------------------------------------------------------------
__global__ __launch_bounds__(256, 2) void fused_edge_kernel(
    const unsigned short* __restrict__ xb,   // bf16 x, [N,128]
    const float* __restrict__ ea,
    const int*   __restrict__ eid_s,
    const int*   __restrict__ src_s,
    const int*   __restrict__ dst_s,
    const unsigned short* __restrict__ Bp,
    float* __restrict__ num,
    float* __restrict__ den,
    float* __restrict__ out_e,
    const float* __restrict__ a_prelu,
    int E) {
  __shared__ __align__(16) char smem[64 * ROWSTRIDE * 2];   // 41,984 B
  unsigned short* At = (unsigned short*)smem;
  float* red = (float*)smem;
  __shared__ int s_src[64];
  __shared__ int s_dst[64];
  __shared__ int s_eid[64];

  const int tid = threadIdx.x;
  const int eb  = blockIdx.x * 64;
  const int nvalid = min(64, E - eb);

  if (tid < 64) {
    int e = 0, s = 0, d = 0;
    if (tid < nvalid) {
      e = eid_s[eb + tid];
      s = src_s[eb + tid];
      d = dst_s[eb + tid];
    }
    s_eid[tid] = e;
    s_src[tid] = s;
    s_dst[tid] = d;
  }
  __syncthreads();

  const ushort8_t* xb8 = (const ushort8_t*)xb;   // row = 16 chunks of 8 bf16
  const float4*    ea4 = (const float4*)ea;

  // gather x[dst] bf16 -> cols [0,128)
  #pragma unroll
  for (int i = tid; i < 1024; i += 256) {
    int r = i >> 4, c = i & 15;
    ushort8_t v = {0, 0, 0, 0, 0, 0, 0, 0};
    if (r < nvalid) v = xb8[(size_t)s_dst[r] * 16 + c];
    *(ushort8_t*)&At[r * ROWSTRIDE + c * 8] = v;
  }
  // gather edge_attr f32 -> cols [128,192)
  #pragma unroll
  for (int i = tid; i < 1024; i += 256) {
    int r = i >> 4, c4 = i & 15;
    float4 v = {0.f, 0.f, 0.f, 0.f};
    if (r < nvalid) v = ea4[(size_t)s_eid[r] * 16 + c4];
    store_bf4(&At[r * ROWSTRIDE + 128 + c4 * 4], v);
  }
  // gather x[src] bf16 -> cols [192,320)
  #pragma unroll
  for (int i = tid; i < 1024; i += 256) {
    int r = i >> 4, c = i & 15;
    ushort8_t v = {0, 0, 0, 0, 0, 0, 0, 0};
    if (r < nvalid) v = xb8[(size_t)s_src[r] * 16 + c];
    *(ushort8_t*)&At[r * ROWSTRIDE + 192 + c * 8] = v;
  }
  __syncthreads();

  const int w    = tid >> 6;
  const int l    = tid & 63;
  const int lrow = l & 15;
  const int lk8  = (l >> 4) << 3;

  f32x4 acc[4][5];
  #pragma unroll
  for (int mt = 0; mt < 4; ++mt)
    #pragma unroll
    for (int i = 0; i < 5; ++i)
      acc[mt][i] = (f32x4){0.f, 0.f, 0.f, 0.f};

  for (int kc = 0; kc < 10; ++kc) {
    const int kbase = kc * 32 + lk8;
    bf16x8 av[4];
    #pragma unroll
    for (int mt = 0; mt < 4; ++mt) {
      ushort8_t u = *(const ushort8_t*)&At[(mt * 16 + lrow) * ROWSTRIDE + kbase];
      av[mt] = __builtin_bit_cast(bf16x8, u);
    }
    #pragma unroll
    for (int i = 0; i < 5; ++i) {
      const int nt = w + 4 * i;
      ushort8_t ub = *(const ushort8_t*)&Bp[(((nt * 10 + kc) * 64) + l) * 8];
      bf16x8 bv = __builtin_bit_cast(bf16x8, ub);
      #pragma unroll
      for (int mt = 0; mt < 4; ++mt)
        acc[mt][i] = __builtin_amdgcn_mfma_f32_16x16x32_bf16(av[mt], bv, acc[mt][i], 0, 0, 0);
    }
  }

  // ------------------- epilogue -------------------
  // C layout: row = (lane>>4)*4 + reg, col = lane&15
  const float slope = a_prelu[0];
  const int rbase = (l >> 4) << 2;
  const int ccol  = l & 15;

  // new_e_feat (tile i=4 is global n-tile w+16 -> e-col = w*16 + ccol)
  #pragma unroll
  for (int mt = 0; mt < 4; ++mt) {
    const int m0 = mt * 16 + rbase;
    #pragma unroll
    for (int r = 0; r < 4; ++r) {
      int m = m0 + r;
      if (m < nvalid)
        out_e[(size_t)s_eid[m] * 64 + w * 16 + ccol] = acc[mt][4][r];
    }
  }

  // ex = exp(prelu(logits))
  float exv[4][2][4];
  #pragma unroll
  for (int mt = 0; mt < 4; ++mt)
    #pragma unroll
    for (int i2 = 0; i2 < 2; ++i2)
      #pragma unroll
      for (int r = 0; r < 4; ++r) {
        float lg = acc[mt][i2][r];
        exv[mt][i2][r] = __expf(lg >= 0.f ? lg : slope * lg);
      }

  __syncthreads();   // done reading At; recycle as `red`

  // ---- pass 1: num = segmented sum of ex*msg over sorted-dst runs ----
  #pragma unroll
  for (int mt = 0; mt < 4; ++mt) {
    const int m0 = mt * 16 + rbase;
    #pragma unroll
    for (int i2 = 0; i2 < 2; ++i2) {
      const int c = (w + 4 * i2) * 16 + ccol;
      #pragma unroll
      for (int r = 0; r < 4; ++r)
        red[(m0 + r) * RED_STRIDE + c] = exv[mt][i2][r] * acc[mt][i2 + 2][r];
    }
  }
  __syncthreads();
  {
    const int c  = tid & 127;
    const int r0 = (tid >> 7) * 32;
    const int r1 = min(r0 + 32, nvalid);
    float sum = 0.f;
    for (int r = r0; r < r1; ++r) {
      sum += red[r * RED_STRIDE + c];
      if (r == r1 - 1 || s_dst[r + 1] != s_dst[r]) {
        unsafeAtomicAdd(&num[(size_t)s_dst[r] * 128 + c], sum);
        sum = 0.f;
      }
    }
  }
  __syncthreads();

  // ---- pass 2: den = segmented sum of ex ----
  #pragma unroll
  for (int mt = 0; mt < 4; ++mt) {
    const int m0 = mt * 16 + rbase;
    #pragma unroll
    for (int i2 = 0; i2 < 2; ++i2) {
      const int c = (w + 4 * i2) * 16 + ccol;
      #pragma unroll
      for (int r = 0; r < 4; ++r)
        red[(m0 + r) * RED_STRIDE + c] = exv[mt][i2][r];
    }
  }
  __syncthreads();
  {
    const int c  = tid & 127;
    const int r0 = (tid >> 7) * 32;
    const int r1 = min(r0 + 32, nvalid);
    float sum = 0.f;
    for (int r = r0; r < r1; ++r) {
      sum += red[r * RED_STRIDE + c];
      if (r == r1 - 1 || s_dst[r + 1] != s_dst[r]) {
        unsafeAtomicAdd(&den[(size_t)s_dst[r] * 128 + c], sum);
        sum = 0.f;
      }
    }
  }
}

// ---------------------------------------------------------------------------
__global__ void finalize_kernel(const float* __restrict__ num,
                                const float* __restrict__ den,
                                const float* __restrict__ bT,
                                float* __restrict__ out_x,
                                int total) {
  int i = blockIdx.x * 256 + threadIdx.x;
  if (i < total)
    out_x[i] = num[i] / (den[i] + 1e-16f) + bT[i & 127];
}

extern "C" void kernel_launch(void* const* d_in, const int* in_sizes, int n_in,
                              void* d_out, int out_size, void* d_ws, size_t ws_size,
                              hipStream_t stream) {
  const float* x   = (const float*)d_in[0];
  const int*   ei  = (const int*)d_in[1];
  const float* ea  = (const float*)d_in[2];
  const float* Wa  = (const float*)d_in[3];
  const float* Wt  = (const float*)d_in[4];
  const float* bT  = (const float*)d_in[5];
  const float* We  = (const float*)d_in[6];
  const float* Wee = (const float*)d_in[7];
  const float* ap  = (const float*)d_in[8];

  const int N = in_sizes[0] / 128;          // 50000
  const int E = in_sizes[1] / 2;            // 500000
  const int NB = (N + 255) / 256;           // 196 scan blocks

  // workspace layout (byte offsets)
  char* ws = (char*)d_ws;
  unsigned short* Bp = (unsigned short*)ws;                       // 204,800
  float* num = (float*)(ws + 204800);                             // 25.6 MB
  float* den = num + (size_t)N * 128;                             // 25.6 MB
  int* cnt   = (int*)(ws + 204800 + (size_t)N * 128 * 8);         // 200,704
  int* cur   = cnt + 50176;                                       // 200,704
  int* eid_s = cur + 50176;                                       // 2 MB
  int* src_s = eid_s + 500224;                                    // 2 MB
  int* dst_s = src_s + 500224;                                    // 2 MB
  int* bsum  = dst_s + 500224;                                    // 1 KB
  unsigned short* x_bf16 = (unsigned short*)(bsum + 256);         // 12.8 MB

  float* out_x = (float*)d_out;
  float* out_e = out_x + (size_t)N * 128;

  // zero num, den, cnt (contiguous)
  hipMemsetAsync(num, 0, (size_t)N * 128 * 8 + 50176 * sizeof(int), stream);
  prep_b_kernel<<<400, 256, 0, stream>>>(Wa, Wt, We, Wee, Bp);
  xbf16_kernel<<<(N * 32 + 255) / 256, 256, 0, stream>>>(x, x_bf16, N * 32);
  hist_kernel<<<(E + 255) / 256, 256, 0, stream>>>(ei, cnt, E);
  scan1_kernel<<<NB, 256, 0, stream>>>(cnt, bsum, N);
  scan2_kernel<<<1, 256, 0, stream>>>(bsum, NB);
  scan3_kernel<<<NB, 256, 0, stream>>>(cnt, bsum, cur, N);
  scatter_kernel<<<(E + 255) / 256, 256, 0, stream>>>(ei, cur, eid_s, src_s,
                                                      dst_s, E);
  fused_edge_kernel<<<(E + 63) / 64, 256, 0, stream>>>(
      x_bf16, ea, eid_s, src_s, dst_s, Bp, num, den, out_e, ap, E);
  finalize_kernel<<<((size_t)N * 128 + 255) / 256, 256, 0, stream>>>(
      num, den, bT, out_x, N * 128);
}